// Round 12
// baseline (416.983 us; speedup 1.0000x reference)
//
#include <hip/hip_runtime.h>
#include <hip/hip_bf16.h>

#define B_  2
#define N_  2048
#define C_  1024
#define H_  16
#define HD_ 64
#define QSZ (B_*N_*C_)       // elements per q/k/v buffer
#define QSCALE 0.18033688011112042f   // 0.125 * log2(e): softmax in exp2 domain

typedef __attribute__((ext_vector_type(8))) short short8;            // 8 bf16
typedef __attribute__((ext_vector_type(4))) float floatx4;

__device__ __forceinline__ unsigned short f2bf(float f) {
    unsigned int u = __builtin_bit_cast(unsigned int, f);
    u += 0x7fff + ((u >> 16) & 1);          // round-to-nearest-even
    return (unsigned short)(u >> 16);
}
// pack two fp32 -> two RNE bf16 in one u32 (lo = a, hi = b) via v_perm_b32
__device__ __forceinline__ unsigned int pk2bf(float a, float b) {
    unsigned int ua = __builtin_bit_cast(unsigned int, a);
    unsigned int ub = __builtin_bit_cast(unsigned int, b);
    ua += 0x7fff + ((ua >> 16) & 1);
    ub += 0x7fff + ((ub >> 16) & 1);
    return __builtin_amdgcn_perm(ub, ua, 0x07060302);
}

// async global->LDS, 16 B per lane; LDS dest = wave-uniform base + lane*16
__device__ __forceinline__ void g2l16(const void* g, void* l) {
    __builtin_amdgcn_global_load_lds(
        (const __attribute__((address_space(1))) void*)g,
        (__attribute__((address_space(3))) void*)l, 16, 0, 0);
}

// ---------------------------------------------------------------------------
// pack fp32 -> bf16, same layout
// ---------------------------------------------------------------------------
__global__ __launch_bounds__(256) void pack_bf16_kernel(
    const float* __restrict__ src, unsigned short* __restrict__ dst)
{
    const int i = blockIdx.x * 256 + threadIdx.x;
    float4 v = ((const float4*)src)[i];
    ushort4 o = {f2bf(v.x), f2bf(v.y), f2bf(v.z), f2bf(v.w)};
    ((ushort4*)dst)[i] = o;
}

// ---------------------------------------------------------------------------
// transpose + pack BOTH weights in one launch
// ---------------------------------------------------------------------------
__global__ __launch_bounds__(256) void transpose_pack2_kernel(
    const float* __restrict__ Wq, unsigned short* __restrict__ Wqt,
    const float* __restrict__ Wp, unsigned short* __restrict__ Wpt)
{
    __shared__ unsigned short tl[32][34];
    const bool isq = blockIdx.x < 96;
    const int bx = isq ? blockIdx.x : blockIdx.x - 96;
    const int Nd = isq ? 3072 : 1024;
    const float* W = isq ? Wq : Wp;
    unsigned short* Wt = isq ? Wqt : Wpt;
    const int r  = threadIdx.x >> 3;
    const int c4 = (threadIdx.x & 7) * 4;
    const int n0 = bx * 32, k0 = blockIdx.y * 32;
    float4 v = *(const float4*)&W[(size_t)(k0 + r) * Nd + n0 + c4];
    tl[r][c4 + 0] = f2bf(v.x); tl[r][c4 + 1] = f2bf(v.y);
    tl[r][c4 + 2] = f2bf(v.z); tl[r][c4 + 3] = f2bf(v.w);
    __syncthreads();
    ushort4 o = {tl[c4 + 0][r], tl[c4 + 1][r], tl[c4 + 2][r], tl[c4 + 3][r]};
    *(ushort4*)&Wt[(size_t)(n0 + r) * 1024 + k0 + c4] = o;
}

// ---------------------------------------------------------------------------
// bf16 MFMA GEMM core (m97 structure): 128x128 tile, BK=32, 4 waves
// ---------------------------------------------------------------------------
#define GEMM_CORE(A_, Bt_, Kd_, row0_, col0_)                                 \
    __shared__ unsigned short As[128 * 32];                                   \
    __shared__ unsigned short Bs[128 * 32];                                   \
    const int t    = threadIdx.x;                                             \
    const int lane = t & 63;                                                  \
    const int w    = t >> 6;                                                  \
    const int l15  = lane & 15;                                               \
    const int quad = lane >> 4;                                               \
    const int wm   = w >> 1, wn = w & 1;                                      \
    size_t aOff = (size_t)(row0_ + w * 16 + (lane >> 2)) * Kd_ + (lane & 3) * 8; \
    size_t bOff = (size_t)(col0_ + w * 16 + (lane >> 2)) * Kd_ + (lane & 3) * 8; \
    floatx4 acc[4][4];                                                        \
    _Pragma("unroll")                                                         \
    for (int i = 0; i < 4; ++i)                                               \
        _Pragma("unroll")                                                     \
        for (int j = 0; j < 4; ++j) acc[i][j] = floatx4{0.f, 0.f, 0.f, 0.f};  \
    for (int k0 = 0; k0 < Kd_; k0 += 32) {                                    \
        _Pragma("unroll")                                                     \
        for (int c = 0; c < 2; ++c) {                                         \
            g2l16(&A_[aOff + (size_t)c * 64 * Kd_ + k0],                      \
                  &As[(w * 16 + c * 64) * 32]);                               \
            g2l16(&Bt_[bOff + (size_t)c * 64 * Kd_ + k0],                     \
                  &Bs[(w * 16 + c * 64) * 32]);                               \
        }                                                                     \
        __syncthreads();                                                      \
        short8 af[4], bf[4];                                                  \
        _Pragma("unroll")                                                     \
        for (int i = 0; i < 4; ++i)                                           \
            af[i] = *(const short8*)&As[(wm * 64 + i * 16 + l15) * 32 + quad * 8]; \
        _Pragma("unroll")                                                     \
        for (int j = 0; j < 4; ++j)                                           \
            bf[j] = *(const short8*)&Bs[(wn * 64 + j * 16 + l15) * 32 + quad * 8]; \
        _Pragma("unroll")                                                     \
        for (int i = 0; i < 4; ++i)                                           \
            _Pragma("unroll")                                                 \
            for (int j = 0; j < 4; ++j)                                       \
                acc[i][j] = __builtin_amdgcn_mfma_f32_16x16x32_bf16(          \
                    af[i], bf[j], acc[i][j], 0, 0, 0);                        \
        __syncthreads();                                                      \
    }

// ---------------------------------------------------------------------------
// Kernel 1: qkv = x @ W_qkv with FUSED per-head LayerNorm on q,k (fp32 math
// on accumulators, before bf16 rounding). q scaled by 0.125*log2(e).
// ---------------------------------------------------------------------------
__global__ __launch_bounds__(256) void gemm_qkv_kernel(
    const unsigned short* __restrict__ X,    // [4096][1024] bf16
    const unsigned short* __restrict__ Wt,   // [3072][1024] bf16 (W^T)
    const float* __restrict__ qn_w, const float* __restrict__ qn_b,
    const float* __restrict__ kn_w, const float* __restrict__ kn_b,
    unsigned short* __restrict__ qb, unsigned short* __restrict__ kb,
    unsigned short* __restrict__ vb)
{
    const int row0 = blockIdx.y * 128;
    const int col0 = blockIdx.x * 128;
    GEMM_CORE(X, Wt, 1024, row0, col0)
    const int which = col0 >> 10;            // 0=q 1=k 2=v, uniform per block
    const int h = ((col0 & 1023) >> 6) + wn; // head index for this wave
    if (which == 2) {
        #pragma unroll
        for (int j = 0; j < 4; ++j) {
            const int d = j * 16 + l15;
            #pragma unroll
            for (int i = 0; i < 4; ++i) {
                #pragma unroll
                for (int r = 0; r < 4; ++r) {
                    const int grow = row0 + wm * 64 + i * 16 + quad * 4 + r;
                    const int bidx = grow >> 11, n = grow & 2047;
                    vb[(((size_t)(bidx * H_ + h) * N_ + n) * HD_) + d] =
                        f2bf(acc[i][j][r]);
                }
            }
        }
    } else {
        const float* wt = (which == 0) ? qn_w : kn_w;
        const float* bi = (which == 0) ? qn_b : kn_b;
        unsigned short* dstbuf = (which == 0) ? qb : kb;
        float w4[4], b4[4];
        #pragma unroll
        for (int j = 0; j < 4; ++j) {
            w4[j] = wt[j * 16 + l15];
            b4[j] = bi[j * 16 + l15];
        }
        #pragma unroll
        for (int i = 0; i < 4; ++i) {
            #pragma unroll
            for (int r = 0; r < 4; ++r) {
                float v0 = acc[i][0][r], v1 = acc[i][1][r],
                      v2 = acc[i][2][r], v3 = acc[i][3][r];
                float s = (v0 + v1) + (v2 + v3);
                #pragma unroll
                for (int o = 1; o < 16; o <<= 1) s += __shfl_xor(s, o);
                const float mu = s * (1.0f / 64.0f);
                const float d0 = v0 - mu, d1 = v1 - mu,
                            d2 = v2 - mu, d3 = v3 - mu;
                float s2 = (d0 * d0 + d1 * d1) + (d2 * d2 + d3 * d3);
                #pragma unroll
                for (int o = 1; o < 16; o <<= 1) s2 += __shfl_xor(s2, o);
                const float rstd = rsqrtf(s2 * (1.0f / 64.0f) + 1e-5f);
                float y0 = d0 * rstd * w4[0] + b4[0];
                float y1 = d1 * rstd * w4[1] + b4[1];
                float y2 = d2 * rstd * w4[2] + b4[2];
                float y3 = d3 * rstd * w4[3] + b4[3];
                if (which == 0) {
                    y0 *= QSCALE; y1 *= QSCALE; y2 *= QSCALE; y3 *= QSCALE;
                }
                const int grow = row0 + wm * 64 + i * 16 + quad * 4 + r;
                const int bidx = grow >> 11, n = grow & 2047;
                unsigned short* dp =
                    &dstbuf[(((size_t)(bidx * H_ + h) * N_ + n) * HD_) + l15];
                dp[0]  = f2bf(y0);
                dp[16] = f2bf(y1);
                dp[32] = f2bf(y2);
                dp[48] = f2bf(y3);
            }
        }
    }
}

// ---------------------------------------------------------------------------
// Kernel 4: out = o @ W_proj + b_proj. 64x128 tile (512 blocks = 2/CU).
// ---------------------------------------------------------------------------
__global__ __launch_bounds__(256) void gemm_proj_kernel(
    const unsigned short* __restrict__ O,    // [4096][1024] bf16
    const unsigned short* __restrict__ Wt,   // [1024][1024] bf16 (W^T)
    const float* __restrict__ bias, float* __restrict__ out)
{
    __shared__ unsigned short As[64 * 32];
    __shared__ unsigned short Bs[128 * 32];
    const int t    = threadIdx.x;
    const int lane = t & 63;
    const int w    = t >> 6;
    const int l15  = lane & 15;
    const int quad = lane >> 4;
    const int row0 = blockIdx.y * 64;
    const int col0 = blockIdx.x * 128;
    size_t aOff = (size_t)(row0 + w * 16 + (lane >> 2)) * 1024 + (lane & 3) * 8;
    size_t bOff = (size_t)(col0 + w * 16 + (lane >> 2)) * 1024 + (lane & 3) * 8;
    floatx4 acc[4][2];
    #pragma unroll
    for (int i = 0; i < 4; ++i)
        #pragma unroll
        for (int j = 0; j < 2; ++j) acc[i][j] = floatx4{0.f, 0.f, 0.f, 0.f};
    for (int k0 = 0; k0 < 1024; k0 += 32) {
        g2l16(&O[aOff + k0], &As[(w * 16) * 32]);
        #pragma unroll
        for (int c = 0; c < 2; ++c)
            g2l16(&Wt[bOff + (size_t)c * 64 * 1024 + k0],
                  &Bs[(w * 16 + c * 64) * 32]);
        __syncthreads();
        short8 af[4], bf[2];
        #pragma unroll
        for (int i = 0; i < 4; ++i)
            af[i] = *(const short8*)&As[(i * 16 + l15) * 32 + quad * 8];
        #pragma unroll
        for (int j = 0; j < 2; ++j)
            bf[j] = *(const short8*)&Bs[(w * 32 + j * 16 + l15) * 32 + quad * 8];
        #pragma unroll
        for (int i = 0; i < 4; ++i)
            #pragma unroll
            for (int j = 0; j < 2; ++j)
                acc[i][j] = __builtin_amdgcn_mfma_f32_16x16x32_bf16(
                    af[i], bf[j], acc[i][j], 0, 0, 0);
        __syncthreads();
    }
    #pragma unroll
    for (int j = 0; j < 2; ++j) {
        const int gcol = col0 + w * 32 + j * 16 + l15;
        const float b = bias[gcol];
        #pragma unroll
        for (int i = 0; i < 4; ++i) {
            #pragma unroll
            for (int r = 0; r < 4; ++r) {
                const int grow = row0 + i * 16 + quad * 4 + r;
                out[(size_t)grow * 1024 + gcol] = acc[i][j][r] + b;
            }
        }
    }
}

// ---------------------------------------------------------------------------
// Kernel 3: flash attention v9 — 8 waves (512 thr), qg(2) x kvq(4) split.
// Wave w: q-half qg=w&1 (64 rows, 4 subtiles) x kv-quarter kvq=w>>1 (32 of
// 128-kv tile, 2 subtiles). Per-wave work halves vs v8 (32 MFMA/iter) while
// total LDS traffic stays at v8's level (each K/Vt frag read by 2 waves).
// 16 waves/CU = 4/SIMD -> pipes overlap (m114). Fixed-ref exp2 softmax:
// 4 kv partials directly addable -> 4-phase LDS accumulate epilogue.
// ---------------------------------------------------------------------------
__global__ __launch_bounds__(512, 4) void flash_kernel(
    const unsigned short* __restrict__ qb, const unsigned short* __restrict__ kb,
    const unsigned short* __restrict__ vb, unsigned short* __restrict__ ob)
{
    __shared__ __align__(16) unsigned short Ks[128 * 72];
    __shared__ __align__(16) unsigned short Vt[64 * 136];    // [d][kv]
    __shared__ __align__(16) unsigned short Pb[128 * 136];   // Q stage -> P -> O(fp32)
    __shared__ float Lb[128];
    const int t    = threadIdx.x;
    const int lane = t & 63;
    const int w    = t >> 6;                 // wave 0..7
    const int qg   = w & 1;                  // q half (64 rows)
    const int kvq  = w >> 1;                 // kv quarter (32 of 128)
    const int l15  = lane & 15;
    const int quad = lane >> 4;
    const int q0   = blockIdx.x * 128;
    const int bh   = blockIdx.y;
    const unsigned short* Q = qb + (size_t)bh * N_ * HD_;
    const unsigned short* K = kb + (size_t)bh * N_ * HD_;
    const unsigned short* V = vb + (size_t)bh * N_ * HD_;

    // stage Q (128x64) into Pb: 512 thr x 2 reps
    {
        const int r = t >> 3, c = (t & 7) * 8;
        *(short8*)&Pb[r * 136 + c] =
            *(const short8*)&Q[(size_t)(q0 + r) * 64 + c];
        *(short8*)&Pb[(r + 64) * 136 + c] =
            *(const short8*)&Q[(size_t)(q0 + r + 64) * 64 + c];
    }
    __syncthreads();
    // Q fragments (B-operand): own 4 q-subtiles (rows qg*64 + qt*16 + l15)
    short8 qf[4][2];
    #pragma unroll
    for (int qt = 0; qt < 4; ++qt)
        #pragma unroll
        for (int kk = 0; kk < 2; ++kk)
            qf[qt][kk] = *(const short8*)
                &Pb[(qg * 64 + qt * 16 + l15) * 136 + kk * 32 + quad * 8];

    floatx4 acc[4][4];
    #pragma unroll
    for (int qt = 0; qt < 4; ++qt)
        #pragma unroll
        for (int dt = 0; dt < 4; ++dt) acc[qt][dt] = floatx4{0.f, 0.f, 0.f, 0.f};
    float l_part[4] = {0.f, 0.f, 0.f, 0.f};

    // staging coords (512 threads): K thread owns (row, 16-col span);
    // V thread owns (kv pair, 8-d slab)
    const int kr = t >> 2, kc = (t & 3) * 16;
    const int vkv = (t & 63) * 2, vd = (t >> 6) * 8;

    short8 kR[2], vR[2];
    kR[0] = *(const short8*)&K[(size_t)kr * 64 + kc];
    kR[1] = *(const short8*)&K[(size_t)kr * 64 + kc + 8];
    vR[0] = *(const short8*)&V[(size_t)vkv * 64 + vd];
    vR[1] = *(const short8*)&V[(size_t)(vkv + 1) * 64 + vd];

    for (int kt = 0; kt < N_; kt += 128) {
        __syncthreads();   // barrier A: prior iter's Ks/Vt/Pb reads complete
        *(short8*)&Ks[kr * 72 + kc]     = kR[0];
        *(short8*)&Ks[kr * 72 + kc + 8] = kR[1];
        #pragma unroll
        for (int j = 0; j < 8; ++j) {
            unsigned int pk = (unsigned int)(unsigned short)vR[0][j] |
                              ((unsigned int)(unsigned short)vR[1][j] << 16);
            *(unsigned int*)&Vt[(vd + j) * 136 + vkv] = pk;
        }
        __syncthreads();   // barrier B: staged tile visible
        // prefetch next tile into regs — latency overlaps compute below
        if (kt + 128 < N_) {
            const int kt2 = kt + 128;
            kR[0] = *(const short8*)&K[(size_t)(kt2 + kr) * 64 + kc];
            kR[1] = *(const short8*)&K[(size_t)(kt2 + kr) * 64 + kc + 8];
            vR[0] = *(const short8*)&V[(size_t)(kt2 + vkv) * 64 + vd];
            vR[1] = *(const short8*)&V[(size_t)(kt2 + vkv + 1) * 64 + vd];
        }

        // S^T + fused fixed-ref softmax: own 2 kv-subtiles x own 4 q-subtiles
        #pragma unroll
        for (int ci = 0; ci < 2; ++ci) {
            const int ct = kvq * 2 + ci;
            short8 a0 = *(const short8*)&Ks[(ct * 16 + l15) * 72 + quad * 8];
            short8 a1 = *(const short8*)&Ks[(ct * 16 + l15) * 72 + 32 + quad * 8];
            #pragma unroll
            for (int qt = 0; qt < 4; ++qt) {
                floatx4 s = {0.f, 0.f, 0.f, 0.f};
                s = __builtin_amdgcn_mfma_f32_16x16x32_bf16(a0, qf[qt][0], s, 0, 0, 0);
                s = __builtin_amdgcn_mfma_f32_16x16x32_bf16(a1, qf[qt][1], s, 0, 0, 0);
                const float p0 = __builtin_amdgcn_exp2f(s[0]);
                const float p1 = __builtin_amdgcn_exp2f(s[1]);
                const float p2 = __builtin_amdgcn_exp2f(s[2]);
                const float p3 = __builtin_amdgcn_exp2f(s[3]);
                l_part[qt] += (p0 + p1) + (p2 + p3);
                uint2 pk;
                pk.x = pk2bf(p0, p1);
                pk.y = pk2bf(p2, p3);
                *(uint2*)&Pb[(qg * 64 + qt * 16 + l15) * 136 + ct * 16 + quad * 4] = pk;
            }
        }
        asm volatile("" ::: "memory");   // same-wave P write -> read ordering

        // O^T partial += V^T[own kv quarter] . P[own rows, own kv quarter]
        {
            const int kk = kvq;
            short8 pbf[4];
            #pragma unroll
            for (int qt = 0; qt < 4; ++qt)
                pbf[qt] = *(const short8*)
                    &Pb[(qg * 64 + qt * 16 + l15) * 136 + kk * 32 + quad * 8];
            #pragma unroll
            for (int dt = 0; dt < 4; ++dt) {
                short8 va = *(const short8*)
                    &Vt[(dt * 16 + l15) * 136 + kk * 32 + quad * 8];
                #pragma unroll
                for (int qt = 0; qt < 4; ++qt)
                    acc[qt][dt] = __builtin_amdgcn_mfma_f32_16x16x32_bf16(
                        va, pbf[qt], acc[qt][dt], 0, 0, 0);
            }
        }
    }

    // reduce l over quads, then 4-phase cross-wave accumulate via fp32 Pb view
    #pragma unroll
    for (int qt = 0; qt < 4; ++qt) {
        l_part[qt] += __shfl_xor(l_part[qt], 16);
        l_part[qt] += __shfl_xor(l_part[qt], 32);
    }
    __syncthreads();                      // all PV reads of Pb done
    float* Pf = (float*)Pb;               // 128 rows x stride 68 fp32
    if (kvq == 0) {
        #pragma unroll
        for (int qt = 0; qt < 4; ++qt) {
            const int q = qg * 64 + qt * 16 + l15;
            #pragma unroll
            for (int dt = 0; dt < 4; ++dt)
                *(floatx4*)&Pf[q * 68 + dt * 16 + quad * 4] = acc[qt][dt];
            if (quad == 0) Lb[q] = l_part[qt];
        }
    }
    __syncthreads();
    #pragma unroll
    for (int ph = 1; ph < 4; ++ph) {
        if (kvq == ph) {
            #pragma unroll
            for (int qt = 0; qt < 4; ++qt) {
                const int q = qg * 64 + qt * 16 + l15;
                #pragma unroll
                for (int dt = 0; dt < 4; ++dt) {
                    floatx4 cur = *(floatx4*)&Pf[q * 68 + dt * 16 + quad * 4];
                    *(floatx4*)&Pf[q * 68 + dt * 16 + quad * 4] = cur + acc[qt][dt];
                }
                if (quad == 0) Lb[q] += l_part[qt];
            }
        }
        __syncthreads();
    }
    // write out: thread t handles rows t>>3 and t>>3+64, 8-d chunk (t&7)*8
    {
        const int r = t >> 3, c = (t & 7) * 8;
        const int bidx = bh >> 4, h = bh & 15;
        #pragma unroll
        for (int rep = 0; rep < 2; ++rep) {
            const int row = r + rep * 64;
            const float inv = 1.0f / Lb[row];
            float4 f0 = *(float4*)&Pf[row * 68 + c];
            float4 f1 = *(float4*)&Pf[row * 68 + c + 4];
            uint4 u;
            u.x = pk2bf(f0.x * inv, f0.y * inv);
            u.y = pk2bf(f0.z * inv, f0.w * inv);
            u.z = pk2bf(f1.x * inv, f1.y * inv);
            u.w = pk2bf(f1.z * inv, f1.w * inv);
            *(uint4*)&ob[((size_t)(bidx * N_ + q0 + row)) * C_ + h * 64 + c] = u;
        }
    }
}

// ---------------------------------------------------------------------------
extern "C" void kernel_launch(void* const* d_in, const int* in_sizes, int n_in,
                              void* d_out, int out_size, void* d_ws, size_t ws_size,
                              hipStream_t stream) {
    const float* x      = (const float*)d_in[0];
    const float* W_qkv  = (const float*)d_in[1];
    const float* qn_w   = (const float*)d_in[2];
    const float* qn_b   = (const float*)d_in[3];
    const float* kn_w   = (const float*)d_in[4];
    const float* kn_b   = (const float*)d_in[5];
    const float* W_proj = (const float*)d_in[6];
    const float* b_proj = (const float*)d_in[7];
    float* out = (float*)d_out;

    unsigned short* qb  = (unsigned short*)d_ws;               // 3 x QSZ bf16
    unsigned short* kb  = qb + (size_t)QSZ;
    unsigned short* vb  = kb + (size_t)QSZ;
    unsigned short* ob  = vb + (size_t)QSZ;                    // [B,N,C] bf16
    unsigned short* xb  = ob + (size_t)B_ * N_ * C_;           // [4096][1024]
    unsigned short* wqt = xb + (size_t)B_ * N_ * C_;           // [3072][1024]
    unsigned short* wpt = wqt + (size_t)3 * C_ * C_;           // [1024][1024]

    pack_bf16_kernel<<<dim3((B_ * N_ * C_) / 1024), 256, 0, stream>>>(x, xb);
    transpose_pack2_kernel<<<dim3(128, 32), 256, 0, stream>>>(W_qkv, wqt, W_proj, wpt);
    gemm_qkv_kernel<<<dim3(24, 32), 256, 0, stream>>>(
        xb, wqt, qn_w, qn_b, kn_w, kn_b, qb, kb, vb);
    flash_kernel<<<dim3(N_ / 128, B_ * H_), 512, 0, stream>>>(qb, kb, vb, ob);
    gemm_proj_kernel<<<dim3(8, 64), 256, 0, stream>>>(ob, wpt, b_proj, out);
}